// Round 12
// baseline (301.610 us; speedup 1.0000x reference)
//
#include <hip/hip_runtime.h>

using short8  = __attribute__((ext_vector_type(8))) short;
using ushort8 = __attribute__((ext_vector_type(8))) unsigned short;
using f32x4   = __attribute__((ext_vector_type(4))) float;
using uint4v  = __attribute__((ext_vector_type(4))) unsigned int;

#define T 4096
#define E 1024
#define NB 2
#define BM 128
#define BN 128
#define BK 32
#define TILE_ELEMS (BM * BK)     // 4096 ushorts = 8 KB
#define TILE_A_W   (256 * BK)    // 8192 ushorts = 16 KB

__device__ __forceinline__ unsigned short f2bf(float f) {
    unsigned int u = __builtin_bit_cast(unsigned int, f);
    u = (u + 0x7FFFu + ((u >> 16) & 1u)) >> 16;
    return (unsigned short)u;
}

// 8 fp32 -> 8 bf16 (RNE) packed in one 16B reg tuple
__device__ __forceinline__ uint4v cvt8(float4 a, float4 b) {
    uint4v u;
    asm("v_cvt_pk_bf16_f32 %0, %1, %2" : "=v"(u[0]) : "v"(a.x), "v"(a.y));
    asm("v_cvt_pk_bf16_f32 %0, %1, %2" : "=v"(u[1]) : "v"(a.z), "v"(a.w));
    asm("v_cvt_pk_bf16_f32 %0, %1, %2" : "=v"(u[2]) : "v"(b.x), "v"(b.y));
    asm("v_cvt_pk_bf16_f32 %0, %1, %2" : "=v"(u[3]) : "v"(b.z), "v"(b.w));
    return u;
}

__device__ __forceinline__ void gld16(const unsigned short* g, unsigned short* l) {
    __builtin_amdgcn_global_load_lds(
        (__attribute__((address_space(1))) void*)g,
        (__attribute__((address_space(3))) void*)l, 16, 0, 0);
}

__device__ __forceinline__ void do_cvt(const float* __restrict__ src,
                                       unsigned short* __restrict__ dst, int blk) {
    size_t i = ((size_t)blk * 256 + threadIdx.x) * 8;
    float4 f0 = *(const float4*)(src + i);
    float4 f1 = *(const float4*)(src + i + 4);
    ushort8 u;
    u[0]=f2bf(f0.x); u[1]=f2bf(f0.y); u[2]=f2bf(f0.z); u[3]=f2bf(f0.w);
    u[4]=f2bf(f1.x); u[5]=f2bf(f1.y); u[6]=f2bf(f1.z); u[7]=f2bf(f1.w);
    *(ushort8*)(dst + i) = u;
}

// v-transpose of one 64x64 tile; tid in [0,256). Caller supplies LDS tile.
__device__ __forceinline__ void do_vt(const float* __restrict__ v,
                                      unsigned short* __restrict__ vt, int id,
                                      float (*tile)[65], int tid) {
    int b   = id / (64 * 16);
    int rem = id % (64 * 16);
    int t0  = (rem / 16) * 64;
    int e0  = (rem % 16) * 64;
    int r   = tid >> 2;
    int c0  = (tid & 3) * 16;
    const float* src = v + ((size_t)(b * T + t0 + r)) * E + e0 + c0;
    #pragma unroll
    for (int i = 0; i < 4; i++) {
        float4 f = *(const float4*)(src + i * 4);
        tile[r][c0 + i*4 + 0] = f.x;
        tile[r][c0 + i*4 + 1] = f.y;
        tile[r][c0 + i*4 + 2] = f.z;
        tile[r][c0 + i*4 + 3] = f.w;
    }
    __syncthreads();
    int er = tid >> 2;
    #pragma unroll
    for (int ch = 0; ch < 2; ch++) {
        int tl = (tid & 3) * 16 + ch * 8;
        ushort8 u;
        #pragma unroll
        for (int j = 0; j < 8; j++) u[j] = f2bf(tile[tl + j][er]);
        *(ushort8*)(vt + ((size_t)(b * E + e0 + er)) * T + t0 + tl) = u;
    }
}

// prologue: [0,4096) q-cvt | [4096,4128) zero lsum.  K is no longer
// pre-converted — pass1 reg-stages it from fp32 directly.
__global__ __launch_bounds__(256) void prologue(const float* __restrict__ q,
                                                unsigned short* __restrict__ qb,
                                                float* __restrict__ lsum) {
    int bid = blockIdx.x;
    if (bid < 4096) do_cvt(q, qb, bid);
    else            lsum[(bid - 4096) * 256 + threadIdx.x] = 0.0f;
}
__global__ __launch_bounds__(256) void v_transpose(const float* __restrict__ v,
                                                   unsigned short* __restrict__ vt) {
    __shared__ float tile[64][65];
    do_vt(v, vt, blockIdx.x, tile, threadIdx.x);
}

// ---------------------------------------------------------------------------
// Pass-2 core: 128x128xBK64, 256 threads (4 waves, 2Mx2N). NBUF=2, 64 KB LDS
// -> 2 blocks/CU. HW-verified R2/R4/R7-R11.
// ---------------------------------------------------------------------------
template <int KITERS>
__device__ __forceinline__ void gemm_core64(const unsigned short* Abase, int apitch,
                                            const unsigned short* Bbase, int bpitch,
                                            unsigned short* ldsA, unsigned short* ldsB,
                                            int tid, f32x4 (&acc)[4][4]) {
    constexpr int TILE64 = 128 * 64;         // 8192 ushorts = 16 KB
    const int lane = tid & 63, wave = tid >> 6;
    const int l15 = lane & 15, kq = lane >> 4;
    const int wm = (wave & 1) * 64, wn = (wave >> 1) * 64;

    int goA[4], goB[4], lo[4];
    #pragma unroll
    for (int i = 0; i < 4; i++) {
        int p = i * 256 + tid;
        int r = p >> 3, c = p & 7;
        int sw = c ^ (r & 7);
        goA[i] = r * apitch + sw * 8;
        goB[i] = r * bpitch + sw * 8;
        lo[i] = (i * 256 + wave * 64) * 8;
    }
    int aoff[2][4], boff[2][4];
    #pragma unroll
    for (int mi = 0; mi < 4; mi++) {
        int r = wm + mi * 16 + l15;
        aoff[0][mi] = (r * 8 + (kq ^ (r & 7))) * 8;
        aoff[1][mi] = (r * 8 + ((kq ^ 4) ^ (r & 7))) * 8;
        int rn = wn + mi * 16 + l15;
        boff[0][mi] = (rn * 8 + (kq ^ (rn & 7))) * 8;
        boff[1][mi] = (rn * 8 + ((kq ^ 4) ^ (rn & 7))) * 8;
    }

    #pragma unroll
    for (int i = 0; i < 4; i++) gld16(Abase + goA[i], ldsA + lo[i]);
    #pragma unroll
    for (int i = 0; i < 4; i++) gld16(Bbase + goB[i], ldsB + lo[i]);

    int cbuf = 0;
    for (int kt = 0; kt < KITERS; kt++) {
        int pk = (kt + 1 < KITERS) ? (kt + 1) : 0;
        int ob = cbuf ^ 1;
        asm volatile("s_barrier" ::: "memory");
        #pragma unroll
        for (int i = 0; i < 4; i++) gld16(Abase + goA[i] + pk * 64, ldsA + ob * TILE64 + lo[i]);
        #pragma unroll
        for (int i = 0; i < 4; i++) gld16(Bbase + goB[i] + pk * 64, ldsB + ob * TILE64 + lo[i]);
        asm volatile("s_waitcnt vmcnt(8)" ::: "memory");
        asm volatile("s_barrier" ::: "memory");

        const unsigned short* A = ldsA + cbuf * TILE64;
        const unsigned short* B = ldsB + cbuf * TILE64;
        #pragma unroll
        for (int ks = 0; ks < 2; ks++) {
            short8 af[4], bf[4];
            #pragma unroll
            for (int i = 0; i < 4; i++) {
                af[i] = *(const short8*)(A + aoff[ks][i]);
                bf[i] = *(const short8*)(B + boff[ks][i]);
            }
            #pragma unroll
            for (int mi = 0; mi < 4; mi++)
                #pragma unroll
                for (int ni = 0; ni < 4; ni++)
                    acc[mi][ni] = __builtin_amdgcn_mfma_f32_16x16x32_bf16(af[mi], bf[ni], acc[mi][ni], 0, 0, 0);
        }
        cbuf = ob;
    }
}

// ---------------------------------------------------------------------------
// Pass-1 core: 256x128xBK32, 512 threads, NBUF=2. A (Q, bf16) staged via
// gld16 as in the measured 85.5us core; B (K) reg-staged from fp32:
// 2x float4 load -> cvt_pk -> ds_write_b128 at the same XOR-swizzled slot
// the read side expects. Issue order per iter: B-regs FIRST, then A-gld16,
// so vmcnt(2) after MFMA drains B(kt+1) while A(kt+1) stays in flight
// across the barrier; top gate vmcnt(4) drains exactly A(kt).
// ---------------------------------------------------------------------------
template <int KITERS>
__device__ __forceinline__ void gemm_core_wide(const unsigned short* Abase, int apitch,
                                               const float* Bf, int bpitch,
                                               unsigned short* ldsA, unsigned short* ldsB,
                                               int tid, f32x4 (&acc)[4][4]) {
    const int lane = tid & 63, wave = tid >> 6;          // wave 0..7
    const int l15 = lane & 15, kq = lane >> 4;
    const int wm = (wave & 3) * 64, wn = (wave >> 2) * 64;

    const unsigned short* ga[2];
    int lao[2];
    #pragma unroll
    for (int i = 0; i < 2; i++) {
        int p = i * 512 + tid;                            // A: 1024 chunks
        int r = p >> 2;
        int kqw = (p & 3) ^ ((p >> 3) & 3);
        ga[i] = Abase + (size_t)r * apitch + kqw * 8;
        lao[i] = (i * 512 + wave * 64) * 8;
    }
    const float* gbf; int bwo;                            // B: 1 (r,h) unit/thread
    {
        int r = tid >> 2, h = tid & 3;
        gbf = Bf + (size_t)r * bpitch + h * 8;
        bwo = (r * 4 + (h ^ ((r >> 1) & 3))) * 8;         // write-side swizzle = read-side
    }
    int aoff[4], boff[4];
    #pragma unroll
    for (int mi = 0; mi < 4; mi++) {
        int r = wm + mi * 16 + l15;                       // [0,256)
        aoff[mi] = (r * 4 + (kq ^ ((r >> 1) & 3))) * 8;
        int rn = wn + mi * 16 + l15;                      // [0,128)
        boff[mi] = (rn * 4 + (kq ^ ((rn >> 1) & 3))) * 8;
    }

    // prologue: tile 0 -> buffer 0
    gld16(ga[0], ldsA + lao[0]);
    gld16(ga[1], ldsA + lao[1]);
    {
        float4 b0 = *(const float4*)(gbf);
        float4 b1 = *(const float4*)(gbf + 4);
        *(uint4v*)(ldsB + bwo) = cvt8(b0, b1);
    }
    __syncthreads();                                      // drains vm+lgkm

    int cbuf = 0;
    for (int kt = 0; kt < KITERS; kt++) {
        int nxt = (kt + 1 < KITERS) ? (kt + 1) : 0;       // tail reload is harmless
        int obuf = cbuf ^ 1;
        // B-reg loads for kt+1 (oldest in queue -> drainable without A)
        float4 b0 = *(const float4*)(gbf + nxt * BK);
        float4 b1 = *(const float4*)(gbf + nxt * BK + 4);
        // A gld16 for kt+1
        gld16(ga[0] + nxt * BK, ldsA + obuf * TILE_A_W + lao[0]);
        gld16(ga[1] + nxt * BK, ldsA + obuf * TILE_A_W + lao[1]);
        asm volatile("s_waitcnt vmcnt(4)" ::: "memory");  // A(kt) landed; 4 newest fly
        asm volatile("s_barrier" ::: "memory");

        const unsigned short* A = ldsA + cbuf * TILE_A_W;
        const unsigned short* B = ldsB + cbuf * TILE_ELEMS;
        short8 af[4], bfr[4];
        #pragma unroll
        for (int i = 0; i < 4; i++) {
            af[i]  = *(const short8*)(A + aoff[i]);
            bfr[i] = *(const short8*)(B + boff[i]);
        }
        #pragma unroll
        for (int mi = 0; mi < 4; mi++)
            #pragma unroll
            for (int ni = 0; ni < 4; ni++)
                acc[mi][ni] = __builtin_amdgcn_mfma_f32_16x16x32_bf16(af[mi], bfr[ni], acc[mi][ni], 0, 0, 0);

        // B(kt+1) arrived (A(kt+1) still in flight); convert + write to obuf
        asm volatile("s_waitcnt vmcnt(2)" ::: "memory");
        *(uint4v*)(ldsB + obuf * TILE_ELEMS + bwo) = cvt8(b0, b1);
        asm volatile("s_waitcnt lgkmcnt(0)" ::: "memory");
        asm volatile("s_barrier" ::: "memory");
        cbuf = obuf;
    }
}

// Pass 1: blocks [0,1024): P = exp2(scale*log2e*(Q K^T) - 12), lsum += sums.
//         blocks [1024,2048): v-transpose, 2 tiles/block (backfill overlap).
__global__ __launch_bounds__(512, 2) void pass1(const unsigned short* __restrict__ qb,
                                                const float* __restrict__ kf,
                                                const float* __restrict__ v,
                                                unsigned short* __restrict__ vt,
                                                unsigned short* __restrict__ P,
                                                float* __restrict__ lsum) {
    __shared__ unsigned short lds[2 * TILE_A_W + 2 * TILE_ELEMS];  // 48 KB
    const int bx = blockIdx.x;
    const int tid = threadIdx.x;

    if (bx >= 1024) {   // v-transpose tail blocks (block-uniform branch)
        const int vb = bx - 1024;
        float (*tileA)[65] = (float (*)[65])lds;
        float (*tileB)[65] = (float (*)[65])(lds + 8320);   // 16640 B each
        if (tid < 256) do_vt(v, vt, vb * 2,     tileA, tid);
        else           do_vt(v, vt, vb * 2 + 1, tileB, tid - 256);
        return;
    }

    unsigned short* ldsA = lds;                      // 16384 ushorts
    unsigned short* ldsB = lds + 2 * TILE_A_W;       //  8192 ushorts
    const int x = bx & 7, j = bx >> 3;               // j in [0,128)
    const int gm = x * 4 + (j & 3);                  // [0,32): b*16+mt
    const int nt = j >> 2;                           // [0,32)
    const int b = gm >> 4, mt = gm & 15;

    f32x4 acc[4][4];
    #pragma unroll
    for (int i = 0; i < 4; i++)
        #pragma unroll
        for (int jj = 0; jj < 4; jj++) acc[i][jj] = {};

    gemm_core_wide<E / BK>(qb + ((size_t)b * T + mt * 256) * E, E,
                           kf + ((size_t)b * T + nt * BN) * E, E,
                           ldsA, ldsB, tid, acc);

    const int lane = tid & 63, wave = tid >> 6;
    const int wm = (wave & 3) * 64, wn = (wave >> 2) * 64;
    const int quad = lane >> 4, l15 = lane & 15;
    const float sl2 = 0.0625f * 1.44269504089f;
    const int col0 = nt * BN + wn + l15;

    #pragma unroll
    for (int mi = 0; mi < 4; mi++) {
        #pragma unroll
        for (int r = 0; r < 4; r++) {
            int row = mt * 256 + wm + mi * 16 + quad * 4 + r;
            size_t base = ((size_t)b * T + row) * T + col0;
            float s = 0.0f;
            #pragma unroll
            for (int ni = 0; ni < 4; ni++) {
                float p = exp2f(acc[mi][ni][r] * sl2 - 12.0f);
                P[base + ni * 16] = f2bf(p);
                s += p;
            }
            s += __shfl_xor(s, 1);
            s += __shfl_xor(s, 2);
            s += __shfl_xor(s, 4);
            s += __shfl_xor(s, 8);
            if (l15 == 0) atomicAdd(lsum + b * T + row, s);
        }
    }
}

// Pass 2: O = (P @ V) / l ; B operand = VT [b][e][t]  (unchanged)
__global__ __launch_bounds__(256, 2) void pass2(const unsigned short* __restrict__ P,
                                                const unsigned short* __restrict__ vt,
                                                const float* __restrict__ lsum,
                                                float* __restrict__ out) {
    constexpr int TILE64 = 128 * 64;
    __shared__ unsigned short ldsA[2 * TILE64];  // 32 KB
    __shared__ unsigned short ldsB[2 * TILE64];  // 32 KB

    const int bx = blockIdx.x;
    const int x = bx & 7, j = bx >> 3;       // j in [0,64)
    const int gm = x * 8 + (j & 7);          // [0,64): b*32+mt
    const int nt = j >> 3;                   // [0,8)
    const int b = gm >> 5, mt = gm & 31;
    const int tid = threadIdx.x;

    f32x4 acc[4][4];
    #pragma unroll
    for (int i = 0; i < 4; i++)
        #pragma unroll
        for (int jj = 0; jj < 4; jj++) acc[i][jj] = {};

    gemm_core64<T / 64>(P + ((size_t)b * T + mt * 128) * T, T,
                        vt + ((size_t)b * E + nt * 128) * T, T,
                        ldsA, ldsB, tid, acc);

    const int lane = tid & 63, wave = tid >> 6;
    const int wm = (wave & 1) * 64, wn = (wave >> 1) * 64;
    const int quad = lane >> 4, l15 = lane & 15;
    const int col0 = nt * 128 + wn + l15;

    #pragma unroll
    for (int mi = 0; mi < 4; mi++) {
        #pragma unroll
        for (int r = 0; r < 4; r++) {
            int row = mt * 128 + wm + mi * 16 + quad * 4 + r;
            float rl = 1.0f / lsum[b * T + row];
            size_t base = ((size_t)b * T + row) * E + col0;
            #pragma unroll
            for (int ni = 0; ni < 4; ni++)
                out[base + ni * 16] = acc[mi][ni][r] * rl;
        }
    }
}

extern "C" void kernel_launch(void* const* d_in, const int* in_sizes, int n_in,
                              void* d_out, int out_size, void* d_ws, size_t ws_size,
                              hipStream_t stream) {
    const float* q = (const float*)d_in[0];
    const float* k = (const float*)d_in[1];
    const float* v = (const float*)d_in[2];
    float* out = (float*)d_out;

    const size_t QK = (size_t)NB * T * E;
    const size_t PSZ = (size_t)NB * T * T;
    float* lsum = (float*)d_ws;
    unsigned short* qbw = (unsigned short*)((char*)d_ws + 32768);
    unsigned short* kbw = qbw + QK;      // unused now (K read as fp32)
    unsigned short* Pw  = kbw + QK;

    const size_t full_need = 32768 + (3 * QK + PSZ) * sizeof(unsigned short);

    if (ws_size >= full_need) {
        unsigned short* vtw = Pw + PSZ;
        prologue<<<4128, 256, 0, stream>>>(q, qbw, lsum);
        pass1<<<2048, 512, 0, stream>>>(qbw, k, v, vtw, Pw, lsum);
        pass2<<<512, 256, 0, stream>>>(Pw, vtw, lsum, out);
    } else {
        // vt aliases kbw (free now): still written before pass2 only, but
        // keep the conservative serial order: vt built after pass1 would
        // stall pass2 — instead alias into kbw which nothing touches.
        unsigned short* vtw = kbw;
        prologue<<<4128, 256, 0, stream>>>(q, qbw, lsum);
        v_transpose<<<NB * 64 * 16, 256, 0, stream>>>(v, vtw);
        pass1<<<1024, 512, 0, stream>>>(qbw, k, v, vtw, Pw, lsum);
        pass2<<<512, 256, 0, stream>>>(Pw, vtw, lsum, out);
    }
}